// Round 2
// baseline (997.060 us; speedup 1.0000x reference)
//
#include <hip/hip_runtime.h>
#include <math.h>

typedef short bf16x8 __attribute__((ext_vector_type(8)));
typedef float floatx4 __attribute__((ext_vector_type(4)));

#define NC 192
#define HH 256
#define WSZ 8
#define NSHIFT 4
#define NHEADS 6

// LDS map (bytes):
//  region A [0, 26112): phase0 xstage (24576, bf16 B-frags, slot-swizzled)
//                       per-head qkvh f32[96 rows=ch][68] (col-rotated by ((row>>3)&3)*16)
//                       after QK^T: attnb f32[32][36] @0 (4608)
//  frags [26112, 40448): 14 frags x 1024 B (q:0-3, k:4-7, v:8-11, a:12-13)
//        per-wave bf16 obuf [64 px][40] (5120 B) aliases frags 0-4 (dead q/k) during AV
#define QKVH_STRIDE 68
#define ATTN_STRIDE 36
#define OB_STRIDE 40            // ushorts
#define FRAG_OFF 26112
#define LDS_TOTAL 40448

#define QKV_FRAG_ELEMS (576 * 192)   // ws: qkv frags then proj frags (bf16)

__device__ __forceinline__ unsigned short f2bf(float f) {
    union { float f; unsigned int u; } v; v.f = f;
    unsigned int u = v.u + 0x7FFFu + ((v.u >> 16) & 1u);
    return (unsigned short)(u >> 16);
}

__device__ __forceinline__ unsigned int pk2(float a, float b) {
    return (unsigned int)f2bf(a) | ((unsigned int)f2bf(b) << 16);
}

// ---- preprocess: swizzle qkv_w / proj_w (f32 row-major) into bf16 MFMA A-frags ----
__global__ void preproc_kernel(const float* __restrict__ qkv_w,
                               const float* __restrict__ proj_w,
                               unsigned short* __restrict__ ws) {
    int e = blockIdx.x * 256 + threadIdx.x;
    if (e < QKV_FRAG_ELEMS) {
        int blk = e >> 9, l = (e >> 3) & 63, j = e & 7;
        int mt = blk / 6, kt = blk % 6;
        ws[e] = f2bf(qkv_w[(mt * 16 + (l & 15)) * NC + kt * 32 + (l >> 4) * 8 + j]);
    } else if (e < QKV_FRAG_ELEMS + NC * NC) {
        int e2 = e - QKV_FRAG_ELEMS;
        int blk = e2 >> 9, l = (e2 >> 3) & 63, j = e2 & 7;
        int mt = blk / 6, kt = blk % 6;
        ws[e] = f2bf(proj_w[(mt * 16 + (l & 15)) * NC + kt * 32 + (l >> 4) * 8 + j]);
    }
}

__global__ __launch_bounds__(256, 4) void attn_main(
    const float* __restrict__ x, const unsigned short* __restrict__ wsA,
    const float* __restrict__ dw_w, const float* __restrict__ temperature,
    float* __restrict__ out)
{
    __shared__ __align__(16) unsigned char smem[LDS_TOTAL];
    float* qkvh = (float*)smem;
    unsigned short* xstage = (unsigned short*)smem;
    float* attnb = (float*)smem;                       // [32][36] (overlaps dead qkvh)
    unsigned short* frags = (unsigned short*)(smem + FRAG_OFF);
    unsigned short* obw   = (unsigned short*)(smem + FRAG_OFF);  // bf16 obuf aliases frags 0-4

    const int t = threadIdx.x;
    const int lane = t & 63;
    const int wv = t >> 6;          // wave id == n-tile (16 px) owned by this wave
    const int quad = lane >> 4;
    const int l15 = lane & 15;
    const int blk = blockIdx.x;
    const int b = blk >> 10, wi = (blk >> 5) & 31, wj = blk & 31;

    // ---- stage x window (rolled -4) into B-frag layout, bf16, channel-paired u32 stores ----
    // logical slot for (c,p): fr = (c>>5)*4 + (p>>4); slot = ((c&31)>>3)<<4 | (p&15); elem j = c&7
    // physical slot = logical ^ (r&3) with r = p>>3  (bank spread for the u32 scatter)
    for (int idx = t; idx < (NC / 2) * 16; idx += 256) {
        int c2 = idx >> 4;              // channel pair index
        int c = c2 * 2;
        int r = (idx >> 1) & 7, s4 = idx & 1;
        int hh = (wi * WSZ + r + NSHIFT) & 255;
        int ww = (wj * WSZ + s4 * 4 + NSHIFT) & 255;
        const float* xb = x + ((size_t)(b * NC + c) * HH + hh) * HH + ww;
        float4 v0 = *((const float4*)xb);
        float4 v1 = *((const float4*)(xb + (size_t)HH * HH));
        int kt = c >> 5, ko = c & 31;   // ko even
        int p0 = r * 8 + s4 * 4;
        int fr = kt * 4 + (p0 >> 4);
        int lxb0 = ((ko >> 3) << 4) | (p0 & 15);         // bits 1-0 are zero
        int m = r & 3;
        unsigned int* dstb = (unsigned int*)xstage + (fr * 64 + lxb0) * 4 + ((ko & 7) >> 1);
        dstb[(0 ^ m) * 4] = pk2(v0.x, v1.x);
        dstb[(1 ^ m) * 4] = pk2(v0.y, v1.y);
        dstb[(2 ^ m) * 4] = pk2(v0.z, v1.z);
        dstb[(3 ^ m) * 4] = pk2(v0.w, v1.w);
    }
    __syncthreads();

    bf16x8 Bx[6];
    {
        int bxor = ((wv & 1) << 1) | ((lane >> 3) & 1);   // = (p>>3)&3 for this lane's px
        #pragma unroll
        for (int kt = 0; kt < 6; ++kt)
            Bx[kt] = *((const bf16x8*)(xstage + ((kt * 4 + wv) * 64 + (lane ^ bxor)) * 8));
    }
    __syncthreads();   // xstage region free -> qkvh

    bf16x8 pB0, pB1, pB2, pB3, pB4, pB5;   // proj B-frags accumulated per head

    #pragma unroll 1
    for (int h = 0; h < NHEADS; ++h) {
        // ---- 1. qkv GEMM for head h: 6 m-tiles of 16 rows (col-rotated store) ----
        #pragma unroll
        for (int mtl = 0; mtl < 6; ++mtl) {
            int part = mtl >> 1, sub = mtl & 1;
            int mt_g = part * 12 + h * 2 + sub;
            const bf16x8* aptr = (const bf16x8*)wsA + (size_t)(mt_g * 6) * 64 + lane;
            floatx4 acc = {0.f, 0.f, 0.f, 0.f};
            #pragma unroll
            for (int kt = 0; kt < 6; ++kt) {
                bf16x8 a = aptr[kt * 64];
                acc = __builtin_amdgcn_mfma_f32_16x16x32_bf16(a, Bx[kt], acc, 0, 0, 0);
            }
            int rowbase = part * 32 + sub * 16 + quad * 4;
            int colp = ((wv * 16 + l15) + (((rowbase >> 3) & 3) << 4)) & 63;
            #pragma unroll
            for (int rg = 0; rg < 4; ++rg)
                qkvh[(rowbase + rg) * QKVH_STRIDE + colp] = acc[rg];
        }
        __syncthreads();   // S1: qkvh visible

        // ---- 2. depthwise 3x3 + (q,k: l2-norm + frag emit) / (v: f32 writeback) ----
        if (t < 192) {
            int ch = t >> 1, half = t & 1;
            int part = ch >> 5;
            int g = part * NC + h * 32 + (ch & 31);
            const float* wp = dw_w + (size_t)g * 9;
            float w[9];
            #pragma unroll
            for (int i = 0; i < 9; ++i) w[i] = wp[i];
            const float* base = qkvh + ch * QKVH_STRIDE;
            int sw16 = ((ch >> 3) & 3) << 4;
            int r0 = half * 4;
            float dwout[4][8];
            float ra[8], rb[8], rc[8];
            auto loadrow = [&](float* dst, int r2) {
                if ((unsigned)r2 < 8u) {
                    float4 lo = *((const float4*)(base + ((r2 * 8 + sw16) & 63)));
                    float4 hi = *((const float4*)(base + ((r2 * 8 + 4 + sw16) & 63)));
                    dst[0]=lo.x; dst[1]=lo.y; dst[2]=lo.z; dst[3]=lo.w;
                    dst[4]=hi.x; dst[5]=hi.y; dst[6]=hi.z; dst[7]=hi.w;
                } else {
                    #pragma unroll
                    for (int i = 0; i < 8; ++i) dst[i] = 0.f;
                }
            };
            auto conv3 = [&](float* o, const float* rm, const float* rz, const float* rp) {
                #pragma unroll
                for (int s = 0; s < 8; ++s) {
                    float acc = w[1]*rm[s] + w[4]*rz[s] + w[7]*rp[s];
                    if (s > 0) acc += w[0]*rm[s-1] + w[3]*rz[s-1] + w[6]*rp[s-1];
                    if (s < 7) acc += w[2]*rm[s+1] + w[5]*rz[s+1] + w[8]*rp[s+1];
                    o[s] = acc;
                }
            };
            loadrow(ra, r0 - 1); loadrow(rb, r0); loadrow(rc, r0 + 1);
            conv3(dwout[0], ra, rb, rc);
            loadrow(ra, r0 + 2); conv3(dwout[1], rb, rc, ra);
            loadrow(rb, r0 + 3); conv3(dwout[2], rc, ra, rb);
            loadrow(rc, r0 + 4); conv3(dwout[3], ra, rb, rc);

            if (part < 2) {
                // q/k: row sum-of-squares (partner t^1 holds other 32 px)
                float ss = 0.f;
                #pragma unroll
                for (int ro = 0; ro < 4; ++ro)
                    #pragma unroll
                    for (int s = 0; s < 8; ++s) ss += dwout[ro][s] * dwout[ro][s];
                ss += __shfl_xor(ss, 1, 64);
                float sc = 1.0f / fmaxf(sqrtf(ss), 1e-12f);
                int mt = (ch & 31) >> 4;
                int fid = part * 4 + mt * 2 + half;
                int x2 = fid & 3;
                unsigned short* fb = frags + fid * 512 + ((ch & 15) ^ x2) * 8;
                #pragma unroll
                for (int ro = 0; ro < 4; ++ro) {
                    bf16x8 o;
                    #pragma unroll
                    for (int s = 0; s < 8; ++s) o[s] = (short)f2bf(dwout[ro][s] * sc);
                    *((bf16x8*)(fb + ro * 128)) = o;
                }
            } else {
                // v: f32 writeback into qkvh (same col rotation)
                float* dst = qkvh + ch * QKVH_STRIDE;
                #pragma unroll
                for (int ro = 0; ro < 4; ++ro) {
                    int c0 = (r0 + ro) * 8;
                    *((float4*)(dst + ((c0 + sw16) & 63)))     = make_float4(dwout[ro][0], dwout[ro][1], dwout[ro][2], dwout[ro][3]);
                    *((float4*)(dst + ((c0 + 4 + sw16) & 63))) = make_float4(dwout[ro][4], dwout[ro][5], dwout[ro][6], dwout[ro][7]);
                }
            }
        }
        __syncthreads();   // S2: q/k frags + v rows ready

        // ---- 3a. QK^T (one 16x16 tile per wave) ----
        {
            int mt = wv >> 1, ntk = wv & 1;
            floatx4 acc = {0.f, 0.f, 0.f, 0.f};
            #pragma unroll
            for (int kt = 0; kt < 2; ++kt) {
                int fq = mt * 2 + kt, fk = ntk * 2 + kt;
                bf16x8 aq = *((const bf16x8*)(frags + fq * 512 + (lane ^ (fq & 3)) * 8));
                bf16x8 bk = *((const bf16x8*)(frags + (4 + fk) * 512 + (lane ^ (fk & 3)) * 8));
                acc = __builtin_amdgcn_mfma_f32_16x16x32_bf16(aq, bk, acc, 0, 0, 0);
            }
            float tmp = temperature[h];
            #pragma unroll
            for (int rg = 0; rg < 4; ++rg)
                attnb[(mt * 16 + quad * 4 + rg) * ATTN_STRIDE + ntk * 16 + l15] = acc[rg] * tmp;
        }
        // ---- 3b. v gather into B-frags (reads rotated qkvh v rows) ----
        {
            int px = wv * 16 + l15;
            int chb = 64 + quad * 8;
            int colp = (px + (quad << 4)) & 63;     // s(row)=quad for v rows
            bf16x8 o;
            #pragma unroll
            for (int j = 0; j < 8; ++j)
                o[j] = (short)f2bf(qkvh[(chb + j) * QKVH_STRIDE + colp]);
            *((bf16x8*)(frags + (8 + wv) * 512 + lane * 8)) = o;
        }
        __syncthreads();   // S3

        // ---- 4. softmax + A-frag emit (threads 0..127: row = t>>2, slice = t&3) ----
        if (t < 128) {
            int row = t >> 2, sl = t & 3;
            const float* src = attnb + row * ATTN_STRIDE + sl * 8;
            float4 lo = *((const float4*)src), hi = *((const float4*)(src + 4));
            float v[8] = {lo.x, lo.y, lo.z, lo.w, hi.x, hi.y, hi.z, hi.w};
            float mx = v[0];
            #pragma unroll
            for (int i = 1; i < 8; ++i) mx = fmaxf(mx, v[i]);
            mx = fmaxf(mx, __shfl_xor(mx, 1, 64));
            mx = fmaxf(mx, __shfl_xor(mx, 2, 64));
            float sum = 0.f;
            #pragma unroll
            for (int i = 0; i < 8; ++i) { v[i] = __expf(v[i] - mx); sum += v[i]; }
            sum += __shfl_xor(sum, 1, 64);
            sum += __shfl_xor(sum, 2, 64);
            float inv = 1.0f / sum;
            bf16x8 o;
            #pragma unroll
            for (int i = 0; i < 8; ++i) o[i] = (short)f2bf(v[i] * inv);
            // slot = sl*16 + (row&15), stored at slot ^ sl (bank spread)
            *((bf16x8*)(frags + (12 + (row >> 4)) * 512 + (sl * 16 + ((row & 15) ^ sl)) * 8)) = o;
        }
        __syncthreads();   // S4

        // ---- 5. attn @ V -> per-wave bf16 obuf (aliases dead q/k frags) ----
        {
            bf16x8 bv = *((const bf16x8*)(frags + (8 + wv) * 512 + lane * 8));
            int axor = (lane >> 4) & 3;
            #pragma unroll
            for (int mt = 0; mt < 2; ++mt) {
                bf16x8 aa = *((const bf16x8*)(frags + (12 + mt) * 512 + (lane ^ axor) * 8));
                floatx4 acc = {0.f, 0.f, 0.f, 0.f};
                acc = __builtin_amdgcn_mfma_f32_16x16x32_bf16(aa, bv, acc, 0, 0, 0);
                int uidx = (wv * 16 + l15) * OB_STRIDE + mt * 16 + quad * 4;   // even
                *((uint2*)((unsigned int*)obw + (uidx >> 1))) =
                    make_uint2(pk2(acc[0], acc[1]), pk2(acc[2], acc[3]));
            }
        }
        // ---- 6. read own wave's obuf rows -> proj B-frag (no barrier: wave-private) ----
        {
            bf16x8 o = *((const bf16x8*)(obw + (wv * 16 + l15) * OB_STRIDE + quad * 8));
            switch (h) {
                case 0: pB0 = o; break;
                case 1: pB1 = o; break;
                case 2: pB2 = o; break;
                case 3: pB3 = o; break;
                case 4: pB4 = o; break;
                default: pB5 = o; break;
            }
        }
    }

    // ---- proj GEMM: 12 m-tiles, nt = wv; direct global store (roll +4) ----
    const bf16x8* apro = (const bf16x8*)(wsA + QKV_FRAG_ELEMS);
    int px = wv * 16 + l15;
    int r = px >> 3, s = px & 7;
    int hh = (wi * WSZ + r + NSHIFT) & 255;
    int ww = (wj * WSZ + s + NSHIFT) & 255;
    #pragma unroll
    for (int mt = 0; mt < 12; ++mt) {
        const bf16x8* ap = apro + (size_t)(mt * 6) * 64 + lane;
        floatx4 acc = {0.f, 0.f, 0.f, 0.f};
        acc = __builtin_amdgcn_mfma_f32_16x16x32_bf16(ap[0 * 64], pB0, acc, 0, 0, 0);
        acc = __builtin_amdgcn_mfma_f32_16x16x32_bf16(ap[1 * 64], pB1, acc, 0, 0, 0);
        acc = __builtin_amdgcn_mfma_f32_16x16x32_bf16(ap[2 * 64], pB2, acc, 0, 0, 0);
        acc = __builtin_amdgcn_mfma_f32_16x16x32_bf16(ap[3 * 64], pB3, acc, 0, 0, 0);
        acc = __builtin_amdgcn_mfma_f32_16x16x32_bf16(ap[4 * 64], pB4, acc, 0, 0, 0);
        acc = __builtin_amdgcn_mfma_f32_16x16x32_bf16(ap[5 * 64], pB5, acc, 0, 0, 0);
        int chb = mt * 16 + quad * 4;
        #pragma unroll
        for (int rg = 0; rg < 4; ++rg)
            out[((size_t)(b * NC + chb + rg) * HH + hh) * HH + ww] = acc[rg];
    }
}

extern "C" void kernel_launch(void* const* d_in, const int* in_sizes, int n_in,
                              void* d_out, int out_size, void* d_ws, size_t ws_size,
                              hipStream_t stream) {
    const float* x           = (const float*)d_in[0];
    const float* qkv_w       = (const float*)d_in[1];
    const float* dw_w        = (const float*)d_in[2];
    const float* proj_w      = (const float*)d_in[3];
    const float* temperature = (const float*)d_in[4];
    float* out = (float*)d_out;
    unsigned short* wsA = (unsigned short*)d_ws;

    int total = QKV_FRAG_ELEMS + NC * NC;
    hipLaunchKernelGGL(preproc_kernel, dim3((total + 255) / 256), dim3(256), 0, stream,
                       qkv_w, proj_w, wsA);
    hipLaunchKernelGGL(attn_main, dim3(4 * 32 * 32), dim3(256), 0, stream,
                       x, wsA, dw_w, temperature, out);
}